// Round 1
// baseline (4809.126 us; speedup 1.0000x reference)
//
#include <hip/hip_runtime.h>

// Conv2d 3x3, stride 1, pad 1, dilation 1.
// x: [32, 18, 256, 256] fp32, w: [64, 18, 3, 3] fp32, bias: [64] fp32
// out: [32, 64, 256, 256] fp32
//
// V2 changes vs V1 (937 us/dispatch, VALUBusy 37%, Occupancy 34%):
//   - Weight LDS staging chunked: 9 ic at a time (20.25 KB instead of 41.5 KB).
//     LDS no longer caps occupancy at 3 blocks/CU; VGPR (84) now caps at
//     6 blocks/CU = 24 waves/CU (75%). __launch_bounds__(256, 6).
//   - One-shot pre-kernel transposes weights [oc][162] -> ws [162][64] so the
//     per-chunk staging is coalesced float4 copies (fallback path keeps the
//     old stride-162 gather if no workspace is available).
// Everything else (register x-window, [k][oc] broadcast ds_reads, 4 rows x
// 16 oc per thread, coalesced stores) unchanged.

#define N_  32
#define IC_ 18
#define H_  256
#define W_  256
#define OC_ 64
#define KTOT (IC_ * 9)          // 162 taps per oc
#define ICC  9                  // input channels per staging chunk
#define KCH  (ICC * 9)          // 81 taps per chunk
#define CHW  (KCH * OC_)        // 5184 floats = 20.25 KB per chunk

__global__ __launch_bounds__(256)
void transpose_w_kernel(const float* __restrict__ wgt, float* __restrict__ wT) {
    const int i = blockIdx.x * 256 + threadIdx.x;
    if (i < KTOT * OC_) {
        const int k  = i >> 6;          // tap index
        const int oc = i & 63;
        wT[i] = wgt[oc * KTOT + k];     // wT[k][oc]
    }
}

template<bool TRANS>
__global__ __launch_bounds__(256, 6)
void conv3x3_kernel(const float* __restrict__ x,
                    const float* __restrict__ wsrc,  // TRANS ? wT[k][oc] : wgt[oc][k]
                    const float* __restrict__ bias,
                    float* __restrict__ out) {
    __shared__ float wS[CHW];           // [k_local][oc] for current chunk

    const int tid    = threadIdx.x;
    const int tx     = tid & 63;        // output column within tile
    const int wv     = tid >> 6;        // wave id 0..3
    const int ocBase = wv * 16;
    const int w0     = blockIdx.x * 64; // tile col origin
    const int h0     = blockIdx.y * 4;  // tile row origin
    const int n      = blockIdx.z;

    float acc[4][16];
    #pragma unroll
    for (int o = 0; o < 16; ++o) {
        const float b = bias[ocBase + o];   // wave-uniform -> s_load
        #pragma unroll
        for (int ty = 0; ty < 4; ++ty) acc[ty][o] = b;
    }

    const float* xn = x + (size_t)n * IC_ * H_ * W_;

    for (int c = 0; c < IC_ / ICC; ++c) {
        __syncthreads();                 // LDS reuse guard (cheap; 2 iters)
        if (TRANS) {
            // Coalesced float4 copy of this chunk's [k][oc] slab.
            const float4* src = (const float4*)(wsrc + c * CHW);
            float4*       dst = (float4*)wS;
            for (int i = tid; i < CHW / 4; i += 256) dst[i] = src[i];
        } else {
            // Fallback: gather from original [oc][k] layout.
            for (int i = tid; i < CHW; i += 256) {
                const int k  = i >> 6;
                const int oc = i & 63;
                wS[i] = wsrc[oc * KTOT + c * KCH + k];
            }
        }
        __syncthreads();

        for (int ici = 0; ici < ICC; ++ici) {
            const float* xc = xn + (c * ICC + ici) * (H_ * W_);

            // Register window: 6 rows x 3 cols of x around this lane's column.
            float xv[6][3];
            #pragma unroll
            for (int r = 0; r < 6; ++r) {
                const int gh = h0 - 1 + r;
                const bool rowOK = (unsigned)gh < (unsigned)H_;
                #pragma unroll
                for (int kw = 0; kw < 3; ++kw) {
                    const int gw = w0 - 1 + tx + kw;
                    const bool ok = rowOK && ((unsigned)gw < (unsigned)W_);
                    xv[r][kw] = ok ? xc[gh * W_ + gw] : 0.0f;
                }
            }

            #pragma unroll
            for (int kh = 0; kh < 3; ++kh) {
                #pragma unroll
                for (int kw = 0; kw < 3; ++kw) {
                    const float* wp = &wS[((ici * 3 + kh) * 3 + kw) * OC_ + ocBase];
                    float wr[16];
                    #pragma unroll
                    for (int o = 0; o < 16; ++o) wr[o] = wp[o]; // 4x ds_read_b128 broadcast
                    #pragma unroll
                    for (int ty = 0; ty < 4; ++ty) {
                        const float xs = xv[ty + kh][kw];
                        #pragma unroll
                        for (int o = 0; o < 16; ++o)
                            acc[ty][o] = fmaf(xs, wr[o], acc[ty][o]);
                    }
                }
            }
        }
    }

    // Epilogue: coalesced stores (lanes = consecutive columns).
    #pragma unroll
    for (int o = 0; o < 16; ++o) {
        const int oc = ocBase + o;
        float* op = out + (((size_t)n * OC_ + oc) * H_ + h0) * (size_t)W_ + w0 + tx;
        #pragma unroll
        for (int ty = 0; ty < 4; ++ty)
            op[ty * W_] = acc[ty][o];
    }
}

extern "C" void kernel_launch(void* const* d_in, const int* in_sizes, int n_in,
                              void* d_out, int out_size, void* d_ws, size_t ws_size,
                              hipStream_t stream) {
    const float* x    = (const float*)d_in[0];
    const float* wgt  = (const float*)d_in[1];
    const float* bias = (const float*)d_in[2];
    float* out        = (float*)d_out;

    const size_t wT_bytes = (size_t)KTOT * OC_ * sizeof(float);  // 41472 B
    dim3 grid(W_ / 64, H_ / 4, N_);   // 4 x 64 x 32 = 8192 blocks
    dim3 block(256);

    if (d_ws != nullptr && ws_size >= wT_bytes) {
        float* wT = (float*)d_ws;
        hipLaunchKernelGGL(transpose_w_kernel,
                           dim3((KTOT * OC_ + 255) / 256), block, 0, stream,
                           wgt, wT);
        hipLaunchKernelGGL(conv3x3_kernel<true>, grid, block, 0, stream,
                           x, wT, bias, out);
    } else {
        hipLaunchKernelGGL(conv3x3_kernel<false>, grid, block, 0, stream,
                           x, wgt, bias, out);
    }
}